// Round 2
// baseline (142.512 us; speedup 1.0000x reference)
//
#include <hip/hip_runtime.h>

// QPLayer: per-batch dual QP via 400 fixed PGD iterations.
// Math: q = b (x cancels), M = 2*A*A^T (rank 4), L = 2*||A^T A||_F + 1e-6,
//       alpha = 1/L, lam <- relu(lam - alpha*b - 2*alpha*A(A^T lam)), out = -A^T lam.
// Pre-scale: A' = sqrt(2*alpha)*A so the iteration is
//       lam <- relu(lam - alpha*b - A'(A'^T lam));   out = -(1/sqrt(2*alpha)) * A'^T lam.
// Decomposition: 8 lanes per problem; lane j owns rows 4j..4j+3 (4 rows) and the
// matching 4 lam entries. Cross-lane: 3-stage DPP butterfly within aligned 8-lane
// groups (quad xor1, quad xor2, row_half_mirror) -> all 8 lanes hold the sum.
// 32768 problems * 8 lanes = 262144 threads = 4096 waves = 4 waves/SIMD.

#define QP_ITERS 400

template <int CTRL>
__device__ __forceinline__ float dpp_add(float v) {
    // fused v_add_f32_dpp pattern (old = 0, bound_ctrl = 1)
    return v + __int_as_float(
        __builtin_amdgcn_update_dpp(0, __float_as_int(v), CTRL, 0xF, 0xF, true));
}

__device__ __forceinline__ float oct_sum(float v) {
    v = dpp_add<0xB1>(v);   // quad_perm(1,0,3,2): xor 1
    v = dpp_add<0x4E>(v);   // quad_perm(2,3,0,1): xor 2
    v = dpp_add<0x141>(v);  // row_half_mirror: pairs quads 0<->1 within each 8-lane group
    return v;
}

__global__ __launch_bounds__(256) void qp_pgd_kernel(
        const float* __restrict__ A,   // [nprob, 32, 4]
        const float* __restrict__ b,   // [nprob, 32]
        float* __restrict__ out,       // [nprob, 4]
        int nprob) {
    int t = blockIdx.x * blockDim.x + threadIdx.x;
    int p = t >> 3;          // problem index
    int j = t & 7;           // sub-lane within 8-lane group
    if (p >= nprob) return;

    // Lane j owns rows m = 4j .. 4j+3. A rows are 16B-aligned float4s.
    const float4* Ar = reinterpret_cast<const float4*>(A + (size_t)p * 128 + (size_t)j * 16);

    float ax[4], ay[4], az[4], aw[4];
#pragma unroll
    for (int k = 0; k < 4; ++k) {
        float4 r = Ar[k];
        ax[k] = r.x; ay[k] = r.y; az[k] = r.z; aw[k] = r.w;
    }
    float bb[4];
    {
        float4 bv = *reinterpret_cast<const float4*>(b + (size_t)p * 32 + (size_t)j * 4);
        bb[0] = bv.x; bb[1] = bv.y; bb[2] = bv.z; bb[3] = bv.w;
    }

    // ---- alpha = 1 / (2*||A^T A||_F + 1e-6) ----
    float s00 = 0.f, s01 = 0.f, s02 = 0.f, s03 = 0.f;
    float s11 = 0.f, s12 = 0.f, s13 = 0.f;
    float s22 = 0.f, s23 = 0.f, s33 = 0.f;
#pragma unroll
    for (int k = 0; k < 4; ++k) {
        s00 = fmaf(ax[k], ax[k], s00);
        s01 = fmaf(ax[k], ay[k], s01);
        s02 = fmaf(ax[k], az[k], s02);
        s03 = fmaf(ax[k], aw[k], s03);
        s11 = fmaf(ay[k], ay[k], s11);
        s12 = fmaf(ay[k], az[k], s12);
        s13 = fmaf(ay[k], aw[k], s13);
        s22 = fmaf(az[k], az[k], s22);
        s23 = fmaf(az[k], aw[k], s23);
        s33 = fmaf(aw[k], aw[k], s33);
    }
    s00 = oct_sum(s00); s01 = oct_sum(s01); s02 = oct_sum(s02); s03 = oct_sum(s03);
    s11 = oct_sum(s11); s12 = oct_sum(s12); s13 = oct_sum(s13);
    s22 = oct_sum(s22); s23 = oct_sum(s23); s33 = oct_sum(s33);
    float ssq = s00 * s00 + s11 * s11 + s22 * s22 + s33 * s33
              + 2.f * (s01 * s01 + s02 * s02 + s03 * s03
                     + s12 * s12 + s13 * s13 + s23 * s23);
    float L = 2.f * sqrtf(ssq) + 1e-6f;
    float alpha = 1.f / L;
    float sc = sqrtf(2.f * alpha);     // A' = sc * A
    float inv_sc = 1.f / sc;

    // pre-scale A and b
#pragma unroll
    for (int k = 0; k < 4; ++k) {
        ax[k] *= sc; ay[k] *= sc; az[k] *= sc; aw[k] *= sc;
    }
    float c[4];
#pragma unroll
    for (int k = 0; k < 4; ++k) c[k] = alpha * bb[k];

    // ---- 400 PGD iterations ----
    float lam[4];
#pragma unroll
    for (int k = 0; k < 4; ++k) lam[k] = 0.f;

#pragma unroll 2
    for (int it = 0; it < QP_ITERS; ++it) {
        // partial u' = A'^T lam over this lane's 4 rows (4 independent FMA chains)
        float u0 = 0.f, u1 = 0.f, u2 = 0.f, u3 = 0.f;
#pragma unroll
        for (int k = 0; k < 4; ++k) {
            u0 = fmaf(ax[k], lam[k], u0);
            u1 = fmaf(ay[k], lam[k], u1);
            u2 = fmaf(az[k], lam[k], u2);
            u3 = fmaf(aw[k], lam[k], u3);
        }
        u0 = oct_sum(u0); u1 = oct_sum(u1); u2 = oct_sum(u2); u3 = oct_sum(u3);
        // lam[m] = relu(lam[m] - alpha*b[m] - A'[m]·u')
#pragma unroll
        for (int k = 0; k < 4; ++k) {
            float tt = lam[k] - c[k];
            tt = fmaf(ax[k], -u0, tt);
            tt = fmaf(ay[k], -u1, tt);
            tt = fmaf(az[k], -u2, tt);
            tt = fmaf(aw[k], -u3, tt);
            lam[k] = fmaxf(tt, 0.f);
        }
    }

    // ---- output: out = -A^T lam = -(1/sc) * A'^T lam ----
    float u0 = 0.f, u1 = 0.f, u2 = 0.f, u3 = 0.f;
#pragma unroll
    for (int k = 0; k < 4; ++k) {
        u0 = fmaf(ax[k], lam[k], u0);
        u1 = fmaf(ay[k], lam[k], u1);
        u2 = fmaf(az[k], lam[k], u2);
        u3 = fmaf(aw[k], lam[k], u3);
    }
    u0 = oct_sum(u0); u1 = oct_sum(u1); u2 = oct_sum(u2); u3 = oct_sum(u3);
    if (j < 4) {
        float r = (j == 0) ? u0 : (j == 1) ? u1 : (j == 2) ? u2 : u3;
        out[(size_t)p * 4 + j] = -r * inv_sc;
    }
}

extern "C" void kernel_launch(void* const* d_in, const int* in_sizes, int n_in,
                              void* d_out, int out_size, void* d_ws, size_t ws_size,
                              hipStream_t stream) {
    const float* A = (const float*)d_in[0];
    // d_in[1] (x) cancels analytically and is unused.
    const float* b = (const float*)d_in[2];
    float* out = (float*)d_out;

    int nprob = in_sizes[2] / 32;          // B = 32768
    int threads = nprob * 8;               // 8 lanes per problem
    dim3 block(256);
    dim3 grid((threads + 255) / 256);
    hipLaunchKernelGGL(qp_pgd_kernel, grid, block, 0, stream, A, b, out, nprob);
}

// Round 3
// 126.001 us; speedup vs baseline: 1.1310x; 1.1310x over previous
//
#include <hip/hip_runtime.h>

// QPLayer: per-batch dual QP via fixed-point PGD (reference runs 400 iters).
// Math: q = b (x cancels), M = 2*A*A^T (rank 4), L = 2*||A^T A||_F + 1e-6,
//       alpha = 1/L, lam <- relu(lam - alpha*b - 2*alpha*A(A^T lam)), out = -A^T lam.
// Pre-scale: A' = sqrt(2*alpha)*A  =>  lam <- relu(lam - alpha*b - A'(A'^T lam)),
//       out = -(1/sqrt(2*alpha)) * A'^T lam.
// Decomposition (R1 geometry — beat 8-lane): 4 lanes/problem, lane j owns rows
// 8j..8j+7 and the matching 8 lam entries. Cross-lane: 2-stage DPP quad butterfly.
// 32768 problems * 4 lanes = 131072 threads = 2048 waves = 2 waves/SIMD.
//
// __launch_bounds__(256, 4): without the min-waves hint the compiler capped the
// kernel at 32 arch VGPRs and shuttled the ~80 live values through AGPRs
// (v_accvgpr_read/write per use, every iteration) — the R1/R2 hidden 2x cost.
//
// Early exit: PGD here reaches an exact fp32 fixed point (contraction ~0.82/iter);
// once lam is bitwise-stationary over 8 iterations, all remaining iterations are
// bit-identical no-ops, so breaking reproduces lam_400 exactly. Check costs ~2.5%.

#define QP_BLOCKS 50   // 50 * 8 = 400 iterations max

template <int CTRL>
__device__ __forceinline__ float dpp_add(float v) {
    // fused v_add_f32_dpp (old = 0, bound_ctrl = 1)
    return v + __int_as_float(
        __builtin_amdgcn_update_dpp(0, __float_as_int(v), CTRL, 0xF, 0xF, true));
}

__device__ __forceinline__ float quad_sum(float v) {
    v = dpp_add<0xB1>(v);   // quad_perm(1,0,3,2): xor 1
    v = dpp_add<0x4E>(v);   // quad_perm(2,3,0,1): xor 2
    return v;
}

__global__ __launch_bounds__(256, 4) void qp_pgd_kernel(
        const float* __restrict__ A,   // [nprob, 32, 4]
        const float* __restrict__ b,   // [nprob, 32]
        float* __restrict__ out,       // [nprob, 4]
        int nprob) {
    int t = blockIdx.x * blockDim.x + threadIdx.x;
    int p = t >> 2;          // problem index
    int j = t & 3;           // lane within quad
    if (p >= nprob) return;

    const float4* Ar = reinterpret_cast<const float4*>(A + (size_t)p * 128 + (size_t)j * 32);
    const float4* br = reinterpret_cast<const float4*>(b + (size_t)p * 32 + (size_t)j * 8);

    float ax[8], ay[8], az[8], aw[8];
#pragma unroll
    for (int k = 0; k < 8; ++k) {
        float4 r = Ar[k];
        ax[k] = r.x; ay[k] = r.y; az[k] = r.z; aw[k] = r.w;
    }
    float bb[8];
    {
        float4 b0 = br[0], b1 = br[1];
        bb[0] = b0.x; bb[1] = b0.y; bb[2] = b0.z; bb[3] = b0.w;
        bb[4] = b1.x; bb[5] = b1.y; bb[6] = b1.z; bb[7] = b1.w;
    }

    // ---- alpha = 1 / (2*||A^T A||_F + 1e-6) ----
    float s00 = 0.f, s01 = 0.f, s02 = 0.f, s03 = 0.f;
    float s11 = 0.f, s12 = 0.f, s13 = 0.f;
    float s22 = 0.f, s23 = 0.f, s33 = 0.f;
#pragma unroll
    for (int k = 0; k < 8; ++k) {
        s00 = fmaf(ax[k], ax[k], s00);
        s01 = fmaf(ax[k], ay[k], s01);
        s02 = fmaf(ax[k], az[k], s02);
        s03 = fmaf(ax[k], aw[k], s03);
        s11 = fmaf(ay[k], ay[k], s11);
        s12 = fmaf(ay[k], az[k], s12);
        s13 = fmaf(ay[k], aw[k], s13);
        s22 = fmaf(az[k], az[k], s22);
        s23 = fmaf(az[k], aw[k], s23);
        s33 = fmaf(aw[k], aw[k], s33);
    }
    s00 = quad_sum(s00); s01 = quad_sum(s01); s02 = quad_sum(s02); s03 = quad_sum(s03);
    s11 = quad_sum(s11); s12 = quad_sum(s12); s13 = quad_sum(s13);
    s22 = quad_sum(s22); s23 = quad_sum(s23); s33 = quad_sum(s33);
    float ssq = s00 * s00 + s11 * s11 + s22 * s22 + s33 * s33
              + 2.f * (s01 * s01 + s02 * s02 + s03 * s03
                     + s12 * s12 + s13 * s13 + s23 * s23);
    float L = 2.f * sqrtf(ssq) + 1e-6f;
    float alpha = 1.f / L;
    float sc = sqrtf(2.f * alpha);     // A' = sc * A
    float inv_sc = 1.f / sc;

#pragma unroll
    for (int k = 0; k < 8; ++k) {
        ax[k] *= sc; ay[k] *= sc; az[k] *= sc; aw[k] *= sc;
    }
    float c[8];
#pragma unroll
    for (int k = 0; k < 8; ++k) c[k] = alpha * bb[k];

    // ---- PGD iterations with every-8 bitwise-fixed-point check ----
    float lam[8], snap[8];
#pragma unroll
    for (int k = 0; k < 8; ++k) { lam[k] = 0.f; snap[k] = 0.f; }

    for (int blk = 0; blk < QP_BLOCKS; ++blk) {
#pragma unroll
        for (int s = 0; s < 8; ++s) {
            float u0 = 0.f, u1 = 0.f, u2 = 0.f, u3 = 0.f;
#pragma unroll
            for (int k = 0; k < 8; ++k) {
                u0 = fmaf(ax[k], lam[k], u0);
                u1 = fmaf(ay[k], lam[k], u1);
                u2 = fmaf(az[k], lam[k], u2);
                u3 = fmaf(aw[k], lam[k], u3);
            }
            u0 = quad_sum(u0); u1 = quad_sum(u1); u2 = quad_sum(u2); u3 = quad_sum(u3);
#pragma unroll
            for (int k = 0; k < 8; ++k) {
                float tt = lam[k] - c[k];
                tt = fmaf(ax[k], -u0, tt);
                tt = fmaf(ay[k], -u1, tt);
                tt = fmaf(az[k], -u2, tt);
                tt = fmaf(aw[k], -u3, tt);
                lam[k] = fmaxf(tt, 0.f);
            }
        }
        // bitwise fixed-point test: if no lane's lam changed over 8 iters, the
        // remaining iterations are exact no-ops.
        int diff = 0;
#pragma unroll
        for (int k = 0; k < 8; ++k)
            diff |= __float_as_int(lam[k]) ^ __float_as_int(snap[k]);
        if (__all(diff == 0)) break;
#pragma unroll
        for (int k = 0; k < 8; ++k) snap[k] = lam[k];
    }

    // ---- output: out = -A^T lam = -(1/sc) * A'^T lam ----
    float u0 = 0.f, u1 = 0.f, u2 = 0.f, u3 = 0.f;
#pragma unroll
    for (int k = 0; k < 8; ++k) {
        u0 = fmaf(ax[k], lam[k], u0);
        u1 = fmaf(ay[k], lam[k], u1);
        u2 = fmaf(az[k], lam[k], u2);
        u3 = fmaf(aw[k], lam[k], u3);
    }
    u0 = quad_sum(u0); u1 = quad_sum(u1); u2 = quad_sum(u2); u3 = quad_sum(u3);
    float r = (j & 1) ? ((j & 2) ? u3 : u1) : ((j & 2) ? u2 : u0);
    out[(size_t)p * 4 + j] = -r * inv_sc;
}

extern "C" void kernel_launch(void* const* d_in, const int* in_sizes, int n_in,
                              void* d_out, int out_size, void* d_ws, size_t ws_size,
                              hipStream_t stream) {
    const float* A = (const float*)d_in[0];
    // d_in[1] (x) cancels analytically and is unused.
    const float* b = (const float*)d_in[2];
    float* out = (float*)d_out;

    int nprob = in_sizes[2] / 32;          // B = 32768
    int threads = nprob * 4;               // 4 lanes per problem
    dim3 block(256);
    dim3 grid((threads + 255) / 256);
    hipLaunchKernelGGL(qp_pgd_kernel, grid, block, 0, stream, A, b, out, nprob);
}

// Round 4
// 106.530 us; speedup vs baseline: 1.3378x; 1.1828x over previous
//
#include <hip/hip_runtime.h>

// QPLayer: per-batch dual QP via 400 fixed PGD iterations.
// Math: q = b (x cancels), M = 2*A*A^T (rank 4), L = 2*||A^T A||_F + 1e-6,
//       alpha = 1/L, lam <- relu(lam - alpha*b - 2*alpha*A(A^T lam)), out = -A^T lam.
// Pre-scale: A' = sqrt(2*alpha)*A  =>  lam <- relu(lam - alpha*b - A'(A'^T lam)),
//       out = -(1/sqrt(2*alpha)) * A'^T lam.
// Decomposition: 4 lanes/problem (R1 geometry — best so far); lane j owns rows
// 8j..8j+7 and the matching 8 lam entries. Cross-lane: 2-stage DPP quad butterfly.
// 32768 problems * 4 lanes = 131072 threads = 2048 waves = 2 waves/SIMD.
//
// __launch_bounds__(256, 1): R1/R3 showed the allocator capping arch VGPRs at
// 32-36 while ~60 floats stay live -> the rest lived in AGPRs with
// v_accvgpr_read/write shuttling every iteration (~2.2x VALU-pipe inflation;
// no scratch traffic confirmed the spill was AGPR-side). min-waves=1 gives a
// 512-reg budget so all live values fit in arch VGPRs. Grid supplies only
// 2 waves/SIMD, and ~80 VGPRs still allows 6, so occupancy is unaffected.
// Early exit removed: slowest-of-16-problems-per-wave governs; it never paid.

#define QP_ITERS 400

template <int CTRL>
__device__ __forceinline__ float dpp_add(float v) {
    // fused v_add_f32_dpp (old = 0, bound_ctrl = 1)
    return v + __int_as_float(
        __builtin_amdgcn_update_dpp(0, __float_as_int(v), CTRL, 0xF, 0xF, true));
}

__device__ __forceinline__ float quad_sum(float v) {
    v = dpp_add<0xB1>(v);   // quad_perm(1,0,3,2): xor 1
    v = dpp_add<0x4E>(v);   // quad_perm(2,3,0,1): xor 2
    return v;
}

__global__ __launch_bounds__(256, 1) void qp_pgd_kernel(
        const float* __restrict__ A,   // [nprob, 32, 4]
        const float* __restrict__ b,   // [nprob, 32]
        float* __restrict__ out,       // [nprob, 4]
        int nprob) {
    int t = blockIdx.x * blockDim.x + threadIdx.x;
    int p = t >> 2;          // problem index
    int j = t & 3;           // lane within quad
    if (p >= nprob) return;

    const float4* Ar = reinterpret_cast<const float4*>(A + (size_t)p * 128 + (size_t)j * 32);
    const float4* br = reinterpret_cast<const float4*>(b + (size_t)p * 32 + (size_t)j * 8);

    float ax[8], ay[8], az[8], aw[8];
#pragma unroll
    for (int k = 0; k < 8; ++k) {
        float4 r = Ar[k];
        ax[k] = r.x; ay[k] = r.y; az[k] = r.z; aw[k] = r.w;
    }
    float bb[8];
    {
        float4 b0 = br[0], b1 = br[1];
        bb[0] = b0.x; bb[1] = b0.y; bb[2] = b0.z; bb[3] = b0.w;
        bb[4] = b1.x; bb[5] = b1.y; bb[6] = b1.z; bb[7] = b1.w;
    }

    // ---- alpha = 1 / (2*||A^T A||_F + 1e-6) ----
    float s00 = 0.f, s01 = 0.f, s02 = 0.f, s03 = 0.f;
    float s11 = 0.f, s12 = 0.f, s13 = 0.f;
    float s22 = 0.f, s23 = 0.f, s33 = 0.f;
#pragma unroll
    for (int k = 0; k < 8; ++k) {
        s00 = fmaf(ax[k], ax[k], s00);
        s01 = fmaf(ax[k], ay[k], s01);
        s02 = fmaf(ax[k], az[k], s02);
        s03 = fmaf(ax[k], aw[k], s03);
        s11 = fmaf(ay[k], ay[k], s11);
        s12 = fmaf(ay[k], az[k], s12);
        s13 = fmaf(ay[k], aw[k], s13);
        s22 = fmaf(az[k], az[k], s22);
        s23 = fmaf(az[k], aw[k], s23);
        s33 = fmaf(aw[k], aw[k], s33);
    }
    s00 = quad_sum(s00); s01 = quad_sum(s01); s02 = quad_sum(s02); s03 = quad_sum(s03);
    s11 = quad_sum(s11); s12 = quad_sum(s12); s13 = quad_sum(s13);
    s22 = quad_sum(s22); s23 = quad_sum(s23); s33 = quad_sum(s33);
    float ssq = s00 * s00 + s11 * s11 + s22 * s22 + s33 * s33
              + 2.f * (s01 * s01 + s02 * s02 + s03 * s03
                     + s12 * s12 + s13 * s13 + s23 * s23);
    float L = 2.f * sqrtf(ssq) + 1e-6f;
    float alpha = 1.f / L;
    float sc = sqrtf(2.f * alpha);     // A' = sc * A
    float inv_sc = 1.f / sc;

#pragma unroll
    for (int k = 0; k < 8; ++k) {
        ax[k] *= sc; ay[k] *= sc; az[k] *= sc; aw[k] *= sc;
    }
    float c[8];
#pragma unroll
    for (int k = 0; k < 8; ++k) c[k] = alpha * bb[k];

    // ---- 400 PGD iterations ----
    float lam[8];
#pragma unroll
    for (int k = 0; k < 8; ++k) lam[k] = 0.f;

    for (int it = 0; it < QP_ITERS; ++it) {
        // partial u' = A'^T lam over this lane's 8 rows (4 independent FMA chains)
        float u0 = 0.f, u1 = 0.f, u2 = 0.f, u3 = 0.f;
#pragma unroll
        for (int k = 0; k < 8; ++k) {
            u0 = fmaf(ax[k], lam[k], u0);
            u1 = fmaf(ay[k], lam[k], u1);
            u2 = fmaf(az[k], lam[k], u2);
            u3 = fmaf(aw[k], lam[k], u3);
        }
        u0 = quad_sum(u0); u1 = quad_sum(u1); u2 = quad_sum(u2); u3 = quad_sum(u3);
        // lam[m] = relu(lam[m] - alpha*b[m] - A'[m]·u')
#pragma unroll
        for (int k = 0; k < 8; ++k) {
            float tt = lam[k] - c[k];
            tt = fmaf(ax[k], -u0, tt);
            tt = fmaf(ay[k], -u1, tt);
            tt = fmaf(az[k], -u2, tt);
            tt = fmaf(aw[k], -u3, tt);
            lam[k] = fmaxf(tt, 0.f);
        }
    }

    // ---- output: out = -A^T lam = -(1/sc) * A'^T lam ----
    float u0 = 0.f, u1 = 0.f, u2 = 0.f, u3 = 0.f;
#pragma unroll
    for (int k = 0; k < 8; ++k) {
        u0 = fmaf(ax[k], lam[k], u0);
        u1 = fmaf(ay[k], lam[k], u1);
        u2 = fmaf(az[k], lam[k], u2);
        u3 = fmaf(aw[k], lam[k], u3);
    }
    u0 = quad_sum(u0); u1 = quad_sum(u1); u2 = quad_sum(u2); u3 = quad_sum(u3);
    float r = (j & 1) ? ((j & 2) ? u3 : u1) : ((j & 2) ? u2 : u0);
    out[(size_t)p * 4 + j] = -r * inv_sc;
}

extern "C" void kernel_launch(void* const* d_in, const int* in_sizes, int n_in,
                              void* d_out, int out_size, void* d_ws, size_t ws_size,
                              hipStream_t stream) {
    const float* A = (const float*)d_in[0];
    // d_in[1] (x) cancels analytically and is unused.
    const float* b = (const float*)d_in[2];
    float* out = (float*)d_out;

    int nprob = in_sizes[2] / 32;          // B = 32768
    int threads = nprob * 4;               // 4 lanes per problem
    dim3 block(256);
    dim3 grid((threads + 255) / 256);
    hipLaunchKernelGGL(qp_pgd_kernel, grid, block, 0, stream, A, b, out, nprob);
}